// Round 1
// baseline (3279.699 us; speedup 1.0000x reference)
//
#include <hip/hip_runtime.h>
#include <stdint.h>

typedef unsigned short u16;
typedef __bf16 bf16x8 __attribute__((ext_vector_type(8)));
typedef float f32x4 __attribute__((ext_vector_type(4)));

#define N_X   20000
#define NGENE 4264
#define NNODE 24264
#define NEDGE 120000
#define MPAD  24320   // 190 * 128

__device__ inline float b2f(u16 u) {
  union { uint32_t u; float f; } x; x.u = ((uint32_t)u) << 16; return x.f;
}
__device__ inline u16 f2b(float f) {
  union { float f; uint32_t u; } x; x.f = f;
  uint32_t r = x.u + 0x7FFFu + ((x.u >> 16) & 1u);
  return (u16)(r >> 16);
}

__device__ inline void load16_lds(const void* g, void* s) {
  __builtin_amdgcn_global_load_lds(
      (const __attribute__((address_space(1))) void*)g,
      (__attribute__((address_space(3))) void*)s, 16, 0, 0);
}

// ---------------------------------------------------------------------------
// GEMM: C[M][N] = A[M][K] * Bt[N][K]^T, bf16 inputs, f32 accum (MFMA 16x16x32)
// 128x128 tile, BK=64, 256 threads = 4 waves (2x2), each wave 64x64 (4x4 frags)
// EPI 0: f32 store into agg (bounds realM/realN, ld=ldc)
// EPI 1: bf16 store, no bounds (padded buffer)
// EPI 2: bf16 store with bias[col] + relu (col<realN else 0)
// ---------------------------------------------------------------------------
template<int EPI>
__global__ __launch_bounds__(256)
void gemm_bt(const u16* __restrict__ A, int lda,
             const u16* __restrict__ Bt, int ldb,
             void* __restrict__ Cp, int ldc, int nk,
             const float* __restrict__ bias, int realM, int realN)
{
  __shared__ u16 smA[128 * 64];
  __shared__ u16 smB[128 * 64];
  const int tid = threadIdx.x;
  const int w = tid >> 6, lane = tid & 63;
  const int l15 = lane & 15, lk = lane >> 4;
  const int wm = w >> 1, wn = w & 1;
  const size_t m0 = (size_t)blockIdx.y * 128;
  const size_t n0 = (size_t)blockIdx.x * 128;

  // staging source pointers: thread covers row (tid>>3), 16B chunk (tid&7)
  const u16* ga = A  + (m0 + (tid >> 3)) * (size_t)lda + (tid & 7) * 8;
  const u16* gb = Bt + (n0 + (tid >> 3)) * (size_t)ldb + (tid & 7) * 8;

  f32x4 acc[4][4];
  const f32x4 zero = {0.f, 0.f, 0.f, 0.f};
#pragma unroll
  for (int i = 0; i < 4; ++i)
#pragma unroll
    for (int j = 0; j < 4; ++j) acc[i][j] = zero;

  // LDS fragment read bases (elements); fixed per lane across K-loop
  const u16* pa = smA + (wm * 64 + l15) * 64 + lk * 8;
  const u16* pb = smB + (wn * 64 + l15) * 64 + lk * 8;

  for (int kt = 0; kt < nk; ++kt) {
#pragma unroll
    for (int rd = 0; rd < 4; ++rd) {
      load16_lds(ga + (size_t)rd * 32 * lda, smA + rd * 2048 + w * 512);
      load16_lds(gb + (size_t)rd * 32 * ldb, smB + rd * 2048 + w * 512);
    }
    ga += 64; gb += 64;
    __syncthreads();
#pragma unroll
    for (int kk = 0; kk < 2; ++kk) {
      bf16x8 av[4], bv[4];
#pragma unroll
      for (int f = 0; f < 4; ++f) {
        av[f] = *(const bf16x8*)(pa + f * 1024 + kk * 32);
        bv[f] = *(const bf16x8*)(pb + f * 1024 + kk * 32);
      }
#pragma unroll
      for (int i = 0; i < 4; ++i)
#pragma unroll
        for (int j = 0; j < 4; ++j)
          acc[i][j] = __builtin_amdgcn_mfma_f32_16x16x32_bf16(av[i], bv[j], acc[i][j], 0, 0, 0);
    }
    __syncthreads();
  }

  // epilogue: C row = m0 + wm*64 + i*16 + lk*4 + q ; col = n0 + wn*64 + j*16 + l15
  const int crow = wm * 64 + lk * 4;
  const int ccol = wn * 64 + l15;
#pragma unroll
  for (int i = 0; i < 4; ++i) {
#pragma unroll
    for (int q = 0; q < 4; ++q) {
      size_t row = m0 + crow + i * 16 + q;
#pragma unroll
      for (int j = 0; j < 4; ++j) {
        int col = (int)n0 + ccol + j * 16;
        float v = acc[i][j][q];
        if constexpr (EPI == 0) {
          if ((int)row < realM && col < realN)
            ((float*)Cp)[row * (size_t)ldc + col] = v;
        } else if constexpr (EPI == 1) {
          ((u16*)Cp)[row * (size_t)ldc + col] = f2b(v);
        } else {
          float bb = (col < realN) ? bias[col] : 0.f;
          v += bb;
          v = v > 0.f ? v : 0.f;
          ((u16*)Cp)[row * (size_t)ldc + col] = f2b(v);
        }
      }
    }
  }
}

// ---------------------------------------------------------------------------
// pack h = concat(x, gene) -> bf16 [MPAD][1664], zero pad rows/cols
// ---------------------------------------------------------------------------
__global__ void pack_h(const float* __restrict__ x, const float* __restrict__ g,
                       u16* __restrict__ h)
{
  int col = blockIdx.x * 256 + threadIdx.x;
  int row = blockIdx.y;
  if (col >= 1664) return;
  float v = 0.f;
  if (col < 1613) {
    if (row < N_X)        v = x[(size_t)row * 1613 + col];
    else if (row < NNODE) v = g[(size_t)(row - N_X) * 1613 + col];
  }
  h[(size_t)row * 1664 + col] = f2b(v);
}

// ---------------------------------------------------------------------------
// transpose-pack: W[Ksrc][Nsrc] f32 -> Bt[Npad][Kpad] bf16 (zero padded)
// ---------------------------------------------------------------------------
__global__ void pack_bt(const float* __restrict__ W, int Ksrc, int Nsrc,
                        u16* __restrict__ Bt, int Kpad, int Npad)
{
  __shared__ float t[32][33];
  int tx = threadIdx.x & 31, ty = threadIdx.x >> 5;  // 32 x 8
  int k0 = blockIdx.y * 32, n0 = blockIdx.x * 32;
#pragma unroll
  for (int i = 0; i < 32; i += 8) {
    int k = k0 + ty + i, n = n0 + tx;
    t[ty + i][tx] = (k < Ksrc && n < Nsrc) ? W[(size_t)k * Nsrc + n] : 0.f;
  }
  __syncthreads();
#pragma unroll
  for (int i = 0; i < 32; i += 8) {
    int n = n0 + ty + i, k = k0 + tx;
    if (n < Npad && k < Kpad) Bt[(size_t)n * Kpad + k] = f2b(t[tx][ty + i]);
  }
}

// ---------------------------------------------------------------------------
// edge degree counts per (dst, rel), then inverse
// ---------------------------------------------------------------------------
__global__ void count_edges(const int* __restrict__ ei, const int* __restrict__ et,
                            float* __restrict__ cnt)
{
  int e = blockIdx.x * 256 + threadIdx.x;
  if (e < NEDGE) atomicAdd(&cnt[(size_t)ei[NEDGE + e] * 4 + et[e]], 1.0f);
}
__global__ void make_inv(float* __restrict__ cnt, int n)
{
  int i = blockIdx.x * 256 + threadIdx.x;
  if (i < n) cnt[i] = 1.f / fmaxf(cnt[i], 1.f);
}

// ---------------------------------------------------------------------------
// scatter: for edges of relation r: agg[dst][:] += Hr[src][:] * inv[dst][r]
// ---------------------------------------------------------------------------
__global__ void scatter_rel(const u16* __restrict__ Hr, int ldH, int C,
                            const int* __restrict__ ei, const int* __restrict__ et,
                            const float* __restrict__ inv,
                            float* __restrict__ agg, int r)
{
  int e = blockIdx.x;
  if (et[e] != r) return;
  int src = ei[e], dst = ei[NEDGE + e];
  float wgt = inv[(size_t)dst * 4 + r];
  const u16* hrow = Hr + (size_t)src * ldH;
  float* arow = agg + (size_t)dst * C;
  for (int c = threadIdx.x; c < C; c += blockDim.x)
    atomicAdd(&arow[c], b2f(hrow[c]) * wgt);
}

// ---------------------------------------------------------------------------
// finalize: h[row][col] = bf16(relu(agg[row][col] + bias[col])), zero pad
// ---------------------------------------------------------------------------
__global__ void finalize_relu(const float* __restrict__ agg, int C,
                              const float* __restrict__ bias,
                              u16* __restrict__ h, int ldh)
{
  int col = blockIdx.x * 256 + threadIdx.x;
  int row = blockIdx.y;
  if (col >= ldh) return;
  float v = 0.f;
  if (row < NNODE && col < C) {
    v = agg[(size_t)row * C + col] + bias[col];
    v = v > 0.f ? v : 0.f;
  }
  h[(size_t)row * ldh + col] = f2b(v);
}

// ---------------------------------------------------------------------------
// head: z = H3[row][0:400] @ lin2 + b ; out = log_softmax(z)
// ---------------------------------------------------------------------------
__global__ void head_out(const u16* __restrict__ H3, int ld,
                         const float* __restrict__ w2, const float* __restrict__ b2,
                         float* __restrict__ out)
{
  int row = blockIdx.x * 256 + threadIdx.x;
  if (row >= NNODE) return;
  const u16* h = H3 + (size_t)row * ld;
  float z0 = b2[0], z1 = b2[1];
  for (int k = 0; k < 400; ++k) {
    float v = b2f(h[k]);
    z0 = fmaf(v, w2[2 * k], z0);
    z1 = fmaf(v, w2[2 * k + 1], z1);
  }
  float m = fmaxf(z0, z1);
  float lse = m + logf(expf(z0 - m) + expf(z1 - m));
  out[(size_t)row * 2]     = z0 - lse;
  out[(size_t)row * 2 + 1] = z1 - lse;
}

// ---------------------------------------------------------------------------
extern "C" void kernel_launch(void* const* d_in, const int* in_sizes, int n_in,
                              void* d_out, int out_size, void* d_ws, size_t ws_size,
                              hipStream_t stream)
{
  const float* x     = (const float*)d_in[0];
  const int*   ei    = (const int*)d_in[1];
  const int*   et    = (const int*)d_in[2];
  const float* gene  = (const float*)d_in[3];
  const float* W1    = (const float*)d_in[4];
  const float* root1 = (const float*)d_in[5];
  const float* b1    = (const float*)d_in[6];
  const float* W2    = (const float*)d_in[7];
  const float* root2 = (const float*)d_in[8];
  const float* b2v   = (const float*)d_in[9];
  const float* l1w   = (const float*)d_in[10];
  const float* l1b   = (const float*)d_in[11];
  const float* l2w   = (const float*)d_in[12];
  const float* l2b   = (const float*)d_in[13];
  (void)in_sizes; (void)n_in; (void)out_size; (void)ws_size;

  char* ws = (char*)d_ws;
  size_t off = 0;
  auto alloc = [&](size_t bytes) {
    void* p = ws + off;
    off += (bytes + 255) & ~(size_t)255;
    return p;
  };
  // total ~323 MB
  u16*   hbuf = (u16*)alloc((size_t)MPAD * 1664 * 2);   // A matrix (reused each layer)
  u16*   hr   = (u16*)alloc((size_t)MPAD * 1664 * 2);   // per-relation GEMM chunk
  u16*   bt   = (u16*)alloc((size_t)1664 * 1664 * 2);   // packed B^T chunk
  float* agg  = (float*)alloc((size_t)NNODE * 1600 * 4);// f32 accumulator
  float* cnt  = (float*)alloc((size_t)NNODE * 4 * 4);   // per-(dst,rel) inv degree

  // degree counts -> inverse
  hipMemsetAsync(cnt, 0, (size_t)NNODE * 4 * 4, stream);
  count_edges<<<(NEDGE + 255) / 256, 256, 0, stream>>>(ei, et, cnt);
  make_inv<<<(NNODE * 4 + 255) / 256, 256, 0, stream>>>(cnt, NNODE * 4);

  // pack input features
  pack_h<<<dim3(7, MPAD), 256, 0, stream>>>(x, gene, hbuf);

  // ---- Layer 1: K=1613->1664, chunk N=1600->1664
  pack_bt<<<dim3(52, 52), 256, 0, stream>>>(root1, 1613, 1600, bt, 1664, 1664);
  gemm_bt<0><<<dim3(13, 190), 256, 0, stream>>>(hbuf, 1664, bt, 1664, agg, 1600, 26,
                                                nullptr, NNODE, 1600);
  for (int r = 0; r < 4; ++r) {
    pack_bt<<<dim3(52, 52), 256, 0, stream>>>(W1 + (size_t)r * 1613 * 1600, 1613, 1600,
                                              bt, 1664, 1664);
    gemm_bt<1><<<dim3(13, 190), 256, 0, stream>>>(hbuf, 1664, bt, 1664, hr, 1664, 26,
                                                  nullptr, 0, 0);
    scatter_rel<<<NEDGE, 256, 0, stream>>>(hr, 1664, 1600, ei, et, cnt, agg, r);
  }
  finalize_relu<<<dim3(7, MPAD), 256, 0, stream>>>(agg, 1600, b1, hbuf, 1664);

  // ---- Layer 2: K=1600, chunk N=900->1024
  pack_bt<<<dim3(32, 50), 256, 0, stream>>>(root2, 1600, 900, bt, 1600, 1024);
  gemm_bt<0><<<dim3(8, 190), 256, 0, stream>>>(hbuf, 1664, bt, 1600, agg, 900, 25,
                                               nullptr, NNODE, 900);
  for (int r = 0; r < 4; ++r) {
    pack_bt<<<dim3(32, 50), 256, 0, stream>>>(W2 + (size_t)r * 1600 * 900, 1600, 900,
                                              bt, 1600, 1024);
    gemm_bt<1><<<dim3(8, 190), 256, 0, stream>>>(hbuf, 1664, bt, 1600, hr, 1024, 25,
                                                 nullptr, 0, 0);
    scatter_rel<<<NEDGE, 256, 0, stream>>>(hr, 1024, 900, ei, et, cnt, agg, r);
  }
  finalize_relu<<<dim3(4, MPAD), 256, 0, stream>>>(agg, 900, b2v, hbuf, 960);

  // ---- Head: lin1 (K=900->960, N=400->512) with bias+relu, then lin2+log_softmax
  pack_bt<<<dim3(16, 30), 256, 0, stream>>>(l1w, 900, 400, bt, 960, 512);
  gemm_bt<2><<<dim3(4, 190), 256, 0, stream>>>(hbuf, 960, bt, 960, hr, 512, 15,
                                               l1b, MPAD, 400);
  head_out<<<(NNODE + 255) / 256, 256, 0, stream>>>(hr, 512, l2w, l2b, (float*)d_out);
}

// Round 2
// 2597.366 us; speedup vs baseline: 1.2627x; 1.2627x over previous
//
#include <hip/hip_runtime.h>
#include <stdint.h>

typedef unsigned short u16;
typedef __bf16 bf16x8 __attribute__((ext_vector_type(8)));
typedef float f32x4 __attribute__((ext_vector_type(4)));

#define N_X   20000
#define NGENE 4264
#define NNODE 24264
#define NEDGE 120000
#define MPAD  24320   // 190 * 128

__device__ inline float b2f(u16 u) {
  union { uint32_t u; float f; } x; x.u = ((uint32_t)u) << 16; return x.f;
}
__device__ inline u16 f2b(float f) {
  union { float f; uint32_t u; } x; x.f = f;
  uint32_t r = x.u + 0x7FFFu + ((x.u >> 16) & 1u);
  return (u16)(r >> 16);
}

__device__ inline void load16_lds(const void* g, void* s) {
  __builtin_amdgcn_global_load_lds(
      (const __attribute__((address_space(1))) void*)g,
      (__attribute__((address_space(3))) void*)s, 16, 0, 0);
}

// ---------------------------------------------------------------------------
// GEMM core (m97 structure): C[M][N] = A[M][K] * Bt[N][K]^T, bf16 in, f32 acc
// 128x128 tile, BK=64, 256 thr = 4 waves (2x2), wave = 64x64 (4x4 frags)
// EPI 0: f32 store (bounds realM/realN)   EPI 1: bf16 plain store
// EPI 2: bf16 store with bias[col]+relu (col<realN else 0)
// ---------------------------------------------------------------------------
template<int EPI>
__device__ inline void gemm_body(const u16* __restrict__ A, int lda,
                                 const u16* __restrict__ Bt, int ldb,
                                 void* __restrict__ Cp, int ldc, int nk,
                                 const float* __restrict__ bias,
                                 int realM, int realN,
                                 size_t m0, size_t n0,
                                 u16* smA, u16* smB)
{
  const int tid = threadIdx.x;
  const int w = tid >> 6, lane = tid & 63;
  const int l15 = lane & 15, lk = lane >> 4;
  const int wm = w >> 1, wn = w & 1;

  const u16* ga = A  + (m0 + (tid >> 3)) * (size_t)lda + (tid & 7) * 8;
  const u16* gb = Bt + (n0 + (tid >> 3)) * (size_t)ldb + (tid & 7) * 8;

  f32x4 acc[4][4];
  const f32x4 zero = {0.f, 0.f, 0.f, 0.f};
#pragma unroll
  for (int i = 0; i < 4; ++i)
#pragma unroll
    for (int j = 0; j < 4; ++j) acc[i][j] = zero;

  const u16* pa = smA + (wm * 64 + l15) * 64 + lk * 8;
  const u16* pb = smB + (wn * 64 + l15) * 64 + lk * 8;

  for (int kt = 0; kt < nk; ++kt) {
#pragma unroll
    for (int rd = 0; rd < 4; ++rd) {
      load16_lds(ga + (size_t)rd * 32 * lda, smA + rd * 2048 + w * 512);
      load16_lds(gb + (size_t)rd * 32 * ldb, smB + rd * 2048 + w * 512);
    }
    ga += 64; gb += 64;
    __syncthreads();
#pragma unroll
    for (int kk = 0; kk < 2; ++kk) {
      bf16x8 av[4], bv[4];
#pragma unroll
      for (int f = 0; f < 4; ++f) {
        av[f] = *(const bf16x8*)(pa + f * 1024 + kk * 32);
        bv[f] = *(const bf16x8*)(pb + f * 1024 + kk * 32);
      }
#pragma unroll
      for (int i = 0; i < 4; ++i)
#pragma unroll
        for (int j = 0; j < 4; ++j)
          acc[i][j] = __builtin_amdgcn_mfma_f32_16x16x32_bf16(av[i], bv[j], acc[i][j], 0, 0, 0);
    }
    __syncthreads();
  }

  const int crow = wm * 64 + lk * 4;
  const int ccol = wn * 64 + l15;
#pragma unroll
  for (int i = 0; i < 4; ++i) {
#pragma unroll
    for (int q = 0; q < 4; ++q) {
      size_t row = m0 + crow + i * 16 + q;
#pragma unroll
      for (int j = 0; j < 4; ++j) {
        int col = (int)n0 + ccol + j * 16;
        float v = acc[i][j][q];
        if constexpr (EPI == 0) {
          if ((int)row < realM && col < realN)
            ((float*)Cp)[row * (size_t)ldc + col] = v;
        } else if constexpr (EPI == 1) {
          ((u16*)Cp)[row * (size_t)ldc + col] = f2b(v);
        } else {
          float bb = (col < realN) ? bias[col] : 0.f;
          v = (col < realN) ? v + bb : 0.f;
          v = v > 0.f ? v : 0.f;
          ((u16*)Cp)[row * (size_t)ldc + col] = f2b(v);
        }
      }
    }
  }
}

template<int EPI>
__global__ __launch_bounds__(256)
void gemm_bt(const u16* __restrict__ A, int lda,
             const u16* __restrict__ Bt, int ldb,
             void* __restrict__ Cp, int ldc, int nk,
             const float* __restrict__ bias, int realM, int realN)
{
  __shared__ u16 smA[128 * 64];
  __shared__ u16 smB[128 * 64];
  gemm_body<EPI>(A, lda, Bt, ldb, Cp, ldc, nk, bias, realM, realN,
                 (size_t)blockIdx.y * 128, (size_t)blockIdx.x * 128, smA, smB);
}

// Fused variant: 1-D grid, bijective XCD-chunked swizzle (m204), cols-fast
// within each XCD chunk so resident blocks share A row-panels in per-XCD L2.
template<int EPI>
__global__ __launch_bounds__(256)
void gemm_bt_swz(const u16* __restrict__ A, int lda,
                 const u16* __restrict__ Bt, int ldb,
                 void* __restrict__ Cp, int ldc, int nk,
                 const float* __restrict__ bias, int CB, int nwg, int realN)
{
  __shared__ u16 smA[128 * 64];
  __shared__ u16 smB[128 * 64];
  int orig = blockIdx.x;
  int q = nwg >> 3, r = nwg & 7;
  int xcd = orig & 7, li = orig >> 3;
  int wgid = (xcd < r ? xcd * (q + 1) : r * (q + 1) + (xcd - r) * q) + li;
  int brow = wgid / CB, bcol = wgid - brow * CB;
  gemm_body<EPI>(A, lda, Bt, ldb, Cp, ldc, nk, bias, 0, realN,
                 (size_t)brow * 128, (size_t)bcol * 128, smA, smB);
}

// ---------------------------------------------------------------------------
// pack h = concat(x, gene) -> bf16 [MPAD][1664], zero pad rows/cols
// ---------------------------------------------------------------------------
__global__ void pack_h(const float* __restrict__ x, const float* __restrict__ g,
                       u16* __restrict__ h)
{
  int col = blockIdx.x * 256 + threadIdx.x;
  int row = blockIdx.y;
  if (col >= 1664) return;
  float v = 0.f;
  if (col < 1613) {
    if (row < N_X)        v = x[(size_t)row * 1613 + col];
    else if (row < NNODE) v = g[(size_t)(row - N_X) * 1613 + col];
  }
  h[(size_t)row * 1664 + col] = f2b(v);
}

// ---------------------------------------------------------------------------
// transpose-pack: W[Ksrc][Nsrc] f32 -> Bt[Npad][Kpad] bf16 (zero padded)
// ---------------------------------------------------------------------------
__global__ void pack_bt(const float* __restrict__ W, int Ksrc, int Nsrc,
                        u16* __restrict__ Bt, int Kpad, int Npad)
{
  __shared__ float t[32][33];
  int tx = threadIdx.x & 31, ty = threadIdx.x >> 5;  // 32 x 8
  int k0 = blockIdx.y * 32, n0 = blockIdx.x * 32;
#pragma unroll
  for (int i = 0; i < 32; i += 8) {
    int k = k0 + ty + i, n = n0 + tx;
    t[ty + i][tx] = (k < Ksrc && n < Nsrc) ? W[(size_t)k * Nsrc + n] : 0.f;
  }
  __syncthreads();
#pragma unroll
  for (int i = 0; i < 32; i += 8) {
    int n = n0 + ty + i, k = k0 + tx;
    if (n < Npad && k < Kpad) Bt[(size_t)n * Kpad + k] = f2b(t[tx][ty + i]);
  }
}

// ---------------------------------------------------------------------------
// degree counts per (dst, rel) + total per dst; then inverse
// ---------------------------------------------------------------------------
__global__ void count_edges2(const int* __restrict__ ei, const int* __restrict__ et,
                             float* __restrict__ cnt, int* __restrict__ deg)
{
  int e = blockIdx.x * 256 + threadIdx.x;
  if (e < NEDGE) {
    int d = ei[NEDGE + e];
    atomicAdd(&cnt[(size_t)d * 4 + et[e]], 1.0f);
    atomicAdd(&deg[d], 1);
  }
}
__global__ void make_inv(float* __restrict__ cnt, int n)
{
  int i = blockIdx.x * 256 + threadIdx.x;
  if (i < n) cnt[i] = 1.f / fmaxf(cnt[i], 1.f);
}

// exclusive prefix scan of deg[NNODE] -> off[NNODE+1], single block 1024 thr
__global__ void scan_deg(const int* __restrict__ deg, int* __restrict__ off)
{
  __shared__ int s[1024];
  int t = threadIdx.x;
  const int per = (NNODE + 1023) / 1024;
  int start = t * per;
  int end = start + per; if (end > NNODE) end = NNODE;
  int sum = 0;
  for (int i = start; i < end; ++i) sum += deg[i];
  s[t] = sum;
  __syncthreads();
  for (int d = 1; d < 1024; d <<= 1) {
    int v = (t >= d) ? s[t - d] : 0;
    __syncthreads();
    s[t] += v;
    __syncthreads();
  }
  int run = s[t] - sum;  // exclusive prefix of this chunk
  for (int i = start; i < end; ++i) { off[i] = run; run += deg[i]; }
  if (t == 1023) off[NNODE] = s[1023];
}

__global__ void fill_csr(const int* __restrict__ ei,
                         const int* __restrict__ off, int* __restrict__ cur,
                         int* __restrict__ eidx)
{
  int e = blockIdx.x * 256 + threadIdx.x;
  if (e < NEDGE) {
    int d = ei[NEDGE + e];
    int p = off[d] + atomicAdd(&cur[d], 1);
    eidx[p] = e;
  }
}

// ---------------------------------------------------------------------------
// Fused aggregation + bias + relu + bf16 pack.
// HrAll[MPAD][ldH] bf16: chunk 0 = root transform, chunk (1+r) = h @ W_r.
// out[row][c] = relu( root[row][c] + sum_edges inv[row][rel]*Hr[rel][src][c]
//                     + bias[c] ),  c in [0,C);  cols [C,padC) zeroed.
// One block per row (dst node); edge meta cached in LDS.
// ---------------------------------------------------------------------------
__global__ void aggregate_fused(const u16* __restrict__ HrAll, int ldH, int CH,
                                int C, int padC,
                                const float* __restrict__ bias,
                                const float* __restrict__ inv,
                                const int* __restrict__ off,
                                const int* __restrict__ eidx,
                                const int* __restrict__ ei,
                                const int* __restrict__ et,
                                u16* __restrict__ hout, int ldh)
{
  int row = blockIdx.x, tid = threadIdx.x;
  if (row >= NNODE) {  // pad rows -> zeros
    for (int c = tid; c < padC; c += 256) hout[(size_t)row * ldh + c] = 0;
    return;
  }
  __shared__ uint32_t s_base[512];
  __shared__ float    s_w[512];
  int e0 = off[row];
  int ne = off[row + 1] - e0;
  int nl = ne < 512 ? ne : 512;
  for (int j = tid; j < nl; j += 256) {
    int e = eidx[e0 + j];
    int rel = et[e];
    int src = ei[e];
    s_base[j] = (uint32_t)src * (uint32_t)ldH + (uint32_t)(1 + rel) * (uint32_t)CH;
    s_w[j] = inv[(size_t)row * 4 + rel];
  }
  __syncthreads();
  for (int c = tid; c < padC; c += 256) {
    float acc = 0.f;
    if (c < C) {
      acc = b2f(HrAll[(size_t)row * ldH + c]);           // root chunk
      for (int j = 0; j < nl; ++j)
        acc += b2f(HrAll[(size_t)s_base[j] + c]) * s_w[j];
      for (int j2 = nl; j2 < ne; ++j2) {                 // overflow (never in practice)
        int e = eidx[e0 + j2];
        int rel = et[e]; int src = ei[e];
        acc += b2f(HrAll[(size_t)src * ldH + (size_t)(1 + rel) * CH + c])
               * inv[(size_t)row * 4 + rel];
      }
      acc += bias[c];
      acc = acc > 0.f ? acc : 0.f;
    }
    hout[(size_t)row * ldh + c] = f2b(acc);
  }
}

// ---------------------------------------------------------------------------
// fallback-path kernels (round-1 verified)
// ---------------------------------------------------------------------------
__global__ void scatter_rel(const u16* __restrict__ Hr, int ldH, int C,
                            const int* __restrict__ ei, const int* __restrict__ et,
                            const float* __restrict__ inv,
                            float* __restrict__ agg, int r)
{
  int e = blockIdx.x;
  if (et[e] != r) return;
  int src = ei[e], dst = ei[NEDGE + e];
  float wgt = inv[(size_t)dst * 4 + r];
  const u16* hrow = Hr + (size_t)src * ldH;
  float* arow = agg + (size_t)dst * C;
  for (int c = threadIdx.x; c < C; c += blockDim.x)
    atomicAdd(&arow[c], b2f(hrow[c]) * wgt);
}

__global__ void finalize_relu(const float* __restrict__ agg, int C,
                              const float* __restrict__ bias,
                              u16* __restrict__ h, int ldh)
{
  int col = blockIdx.x * 256 + threadIdx.x;
  int row = blockIdx.y;
  if (col >= ldh) return;
  float v = 0.f;
  if (row < NNODE && col < C) {
    v = agg[(size_t)row * C + col] + bias[col];
    v = v > 0.f ? v : 0.f;
  }
  h[(size_t)row * ldh + col] = f2b(v);
}

// ---------------------------------------------------------------------------
// head: z = H3[row][0:400] @ lin2 + b ; out = log_softmax(z)
// ---------------------------------------------------------------------------
__global__ void head_out(const u16* __restrict__ H3, int ld,
                         const float* __restrict__ w2, const float* __restrict__ b2,
                         float* __restrict__ out)
{
  int row = blockIdx.x * 256 + threadIdx.x;
  if (row >= NNODE) return;
  const u16* h = H3 + (size_t)row * ld;
  float z0 = b2[0], z1 = b2[1];
  for (int k = 0; k < 400; ++k) {
    float v = b2f(h[k]);
    z0 = fmaf(v, w2[2 * k], z0);
    z1 = fmaf(v, w2[2 * k + 1], z1);
  }
  float m = fmaxf(z0, z1);
  float lse = m + logf(expf(z0 - m) + expf(z1 - m));
  out[(size_t)row * 2]     = z0 - lse;
  out[(size_t)row * 2 + 1] = z1 - lse;
}

// ---------------------------------------------------------------------------
extern "C" void kernel_launch(void* const* d_in, const int* in_sizes, int n_in,
                              void* d_out, int out_size, void* d_ws, size_t ws_size,
                              hipStream_t stream)
{
  const float* x     = (const float*)d_in[0];
  const int*   ei    = (const int*)d_in[1];
  const int*   et    = (const int*)d_in[2];
  const float* gene  = (const float*)d_in[3];
  const float* W1    = (const float*)d_in[4];
  const float* root1 = (const float*)d_in[5];
  const float* b1    = (const float*)d_in[6];
  const float* W2    = (const float*)d_in[7];
  const float* root2 = (const float*)d_in[8];
  const float* b2v   = (const float*)d_in[9];
  const float* l1w   = (const float*)d_in[10];
  const float* l1b   = (const float*)d_in[11];
  const float* l2w   = (const float*)d_in[12];
  const float* l2b   = (const float*)d_in[13];
  (void)in_sizes; (void)n_in; (void)out_size;

  char* ws = (char*)d_ws;
  size_t off_b = 0;
  auto alloc = [&](size_t bytes) {
    void* p = ws + off_b;
    off_b += (bytes + 255) & ~(size_t)255;
    return p;
  };
  // small arrays (both paths)
  float* cnt  = (float*)alloc((size_t)NNODE * 4 * 4);
  int*   deg  = (int*)alloc((size_t)NNODE * 4);
  int*   offp = (int*)alloc((size_t)(NNODE + 1) * 4);
  int*   cur  = (int*)alloc((size_t)NNODE * 4);
  int*   eidx = (int*)alloc((size_t)NEDGE * 4);

  hipMemsetAsync(cnt, 0, (size_t)NNODE * 4 * 4, stream);
  hipMemsetAsync(deg, 0, (size_t)NNODE * 4, stream);
  hipMemsetAsync(cur, 0, (size_t)NNODE * 4, stream);
  count_edges2<<<(NEDGE + 255) / 256, 256, 0, stream>>>(ei, et, cnt, deg);
  make_inv<<<(NNODE * 4 + 255) / 256, 256, 0, stream>>>(cnt, NNODE * 4);

  const bool big = ws_size >= (size_t)515000000;

  if (big) {
    // fused path: hbuf 81MB, HrAll 405MB, BtAll 28MB  (total ~515MB)
    u16* hbuf  = (u16*)alloc((size_t)MPAD * 1664 * 2);
    u16* HrAll = (u16*)alloc((size_t)MPAD * 8320 * 2);
    u16* BtAll = (u16*)alloc((size_t)8320 * 1664 * 2);

    scan_deg<<<1, 1024, 0, stream>>>(deg, offp);
    fill_csr<<<(NEDGE + 255) / 256, 256, 0, stream>>>(ei, offp, cur, eidx);

    pack_h<<<dim3(7, MPAD), 256, 0, stream>>>(x, gene, hbuf);

    // ---- Layer 1: K=1664 (nk=26), B chunks of 1664 cols: [root1, W1 x4]
    pack_bt<<<dim3(52, 52), 256, 0, stream>>>(root1, 1613, 1600, BtAll, 1664, 1664);
    for (int r = 0; r < 4; ++r)
      pack_bt<<<dim3(52, 52), 256, 0, stream>>>(W1 + (size_t)r * 1613 * 1600, 1613, 1600,
                                                BtAll + (size_t)(1 + r) * 1664 * 1664,
                                                1664, 1664);
    {
      int CB = 65, nwg = 190 * CB;  // 12350
      gemm_bt_swz<1><<<nwg, 256, 0, stream>>>(hbuf, 1664, BtAll, 1664, HrAll, 8320, 26,
                                              nullptr, CB, nwg, 0);
    }
    aggregate_fused<<<MPAD, 256, 0, stream>>>(HrAll, 8320, 1664, 1600, 1664,
                                              b1, cnt, offp, eidx, ei, et, hbuf, 1664);

    // ---- Layer 2: K=1600 (nk=25), B chunks of 1024 cols: [root2, W2 x4]
    pack_bt<<<dim3(32, 50), 256, 0, stream>>>(root2, 1600, 900, BtAll, 1600, 1024);
    for (int r = 0; r < 4; ++r)
      pack_bt<<<dim3(32, 50), 256, 0, stream>>>(W2 + (size_t)r * 1600 * 900, 1600, 900,
                                                BtAll + (size_t)(1 + r) * 1024 * 1600,
                                                1600, 1024);
    {
      int CB = 40, nwg = 190 * CB;  // 7600
      gemm_bt_swz<1><<<nwg, 256, 0, stream>>>(hbuf, 1664, BtAll, 1600, HrAll, 5120, 25,
                                              nullptr, CB, nwg, 0);
    }
    aggregate_fused<<<MPAD, 256, 0, stream>>>(HrAll, 5120, 1024, 900, 960,
                                              b2v, cnt, offp, eidx, ei, et, hbuf, 1664);

    // ---- Head: lin1 (K=960 nk=15, N=512, real 400) bias+relu, then lin2+lsm
    pack_bt<<<dim3(16, 30), 256, 0, stream>>>(l1w, 900, 400, BtAll, 960, 512);
    gemm_bt<2><<<dim3(4, 190), 256, 0, stream>>>(hbuf, 1664, BtAll, 960, HrAll, 512, 15,
                                                 l1b, MPAD, 400);
    head_out<<<(NNODE + 255) / 256, 256, 0, stream>>>(HrAll, 512, l2w, l2b, (float*)d_out);
  } else {
    // fallback: round-1 verified flow (~325MB)
    u16*   hbuf = (u16*)alloc((size_t)MPAD * 1664 * 2);
    u16*   hr   = (u16*)alloc((size_t)MPAD * 1664 * 2);
    u16*   bt   = (u16*)alloc((size_t)1664 * 1664 * 2);
    float* agg  = (float*)alloc((size_t)NNODE * 1600 * 4);

    pack_h<<<dim3(7, MPAD), 256, 0, stream>>>(x, gene, hbuf);

    pack_bt<<<dim3(52, 52), 256, 0, stream>>>(root1, 1613, 1600, bt, 1664, 1664);
    gemm_bt<0><<<dim3(13, 190), 256, 0, stream>>>(hbuf, 1664, bt, 1664, agg, 1600, 26,
                                                  nullptr, NNODE, 1600);
    for (int r = 0; r < 4; ++r) {
      pack_bt<<<dim3(52, 52), 256, 0, stream>>>(W1 + (size_t)r * 1613 * 1600, 1613, 1600,
                                                bt, 1664, 1664);
      gemm_bt<1><<<dim3(13, 190), 256, 0, stream>>>(hbuf, 1664, bt, 1664, hr, 1664, 26,
                                                    nullptr, 0, 0);
      scatter_rel<<<NEDGE, 256, 0, stream>>>(hr, 1664, 1600, ei, et, cnt, agg, r);
    }
    finalize_relu<<<dim3(7, MPAD), 256, 0, stream>>>(agg, 1600, b1, hbuf, 1664);

    pack_bt<<<dim3(32, 50), 256, 0, stream>>>(root2, 1600, 900, bt, 1600, 1024);
    gemm_bt<0><<<dim3(8, 190), 256, 0, stream>>>(hbuf, 1664, bt, 1600, agg, 900, 25,
                                                 nullptr, NNODE, 900);
    for (int r = 0; r < 4; ++r) {
      pack_bt<<<dim3(32, 50), 256, 0, stream>>>(W2 + (size_t)r * 1600 * 900, 1600, 900,
                                                bt, 1600, 1024);
      gemm_bt<1><<<dim3(8, 190), 256, 0, stream>>>(hbuf, 1664, bt, 1600, hr, 1024, 25,
                                                   nullptr, 0, 0);
      scatter_rel<<<NEDGE, 256, 0, stream>>>(hr, 1024, 900, ei, et, cnt, agg, r);
    }
    finalize_relu<<<dim3(4, MPAD), 256, 0, stream>>>(agg, 900, b2v, hbuf, 960);

    pack_bt<<<dim3(16, 30), 256, 0, stream>>>(l1w, 900, 400, bt, 960, 512);
    gemm_bt<2><<<dim3(4, 190), 256, 0, stream>>>(hbuf, 960, bt, 960, hr, 512, 15,
                                                 l1b, MPAD, 400);
    head_out<<<(NNODE + 255) / 256, 256, 0, stream>>>(hr, 512, l2w, l2b, (float*)d_out);
  }
}